// Round 1
// baseline (254.980 us; speedup 1.0000x reference)
//
#include <hip/hip_runtime.h>
#include <math.h>

// R4: sliding-window strip kernel.
//
// R3 evidence: VALUBusy 22.5%, HBM 31%, Occupancy 44%, wave lifetime ~21k cy
// for ~600 cy of issue -> latency/request-bound one-shot waves with 4x read
// amplification (rows t-1,t-2,t-4 re-read per output row; 24 vmem instr/row).
//
// R4 structure: one block = one strip of L_STRIP=16 consecutive t for one b.
// Thread owns 4 columns (float4); window of past rows kept in an 8-slot
// register ring (t0 % 8 == 0 so slot = k & 7 is compile-time after unroll).
// Per row: ONE float4 load/thread (prefetch distance 3) + ONE store.
// vmem per 16-row strip: 20 loads + 16 stores (was 24 instr per row).
// Gate/scalar row sums: intra-wave __shfl_xor butterfly + 64B double-buffered
// LDS cross-wave exchange, one barrier per row.
// XCD swizzle: 2048 strips / 8 XCDs = 256 strips = exactly one batch b per
// XCD -> strip warm-up rows (previous strip's rows) are L2-local.

constexpr int T_DIM   = 4096;
constexpr int D_DIM   = 1024;
constexpr int L_STRIP = 16;   // rows per block
constexpr int PF      = 3;    // prefetch distance (rows)
constexpr int WARM    = 4;    // history rows needed (t-1, t-2, t-4 -> depth 4)

// ds_swizzle quad-perm broadcast patterns: offset[15]=1, offset[7:0]=2-bit sels
constexpr int QB0 = 0x8000;  // all quad lanes <- quad lane 0
constexpr int QB1 = 0x8055;  // all quad lanes <- quad lane 1
constexpr int QB2 = 0x80AA;  // all quad lanes <- quad lane 2

template <int PAT>
__device__ __forceinline__ float swz(float v) {
    return __int_as_float(__builtin_amdgcn_ds_swizzle(__float_as_int(v), PAT));
}

__device__ __forceinline__ float sigmoidf(float z) {
    return 1.0f / (1.0f + __expf(-z));
}

__global__ __launch_bounds__(256, 6) void clifford_kernel(
    const float* __restrict__ x,
    const float* __restrict__ gate_w,
    const float* __restrict__ gate_b,
    const float* __restrict__ scalar_w,
    const float* __restrict__ bivec_w,
    float* __restrict__ out,
    int nstrips)
{
    // XCD-aware swizzle: contiguous strip span per XCD (one b per XCD).
    int blk = blockIdx.x;
    if ((gridDim.x & 7) == 0) {
        const int per = gridDim.x >> 3;
        blk = (blockIdx.x & 7) * per + (blockIdx.x >> 3);
    }
    if (blk >= nstrips) return;

    const int tid  = threadIdx.x;
    const int wid  = tid >> 6;
    const int lane = tid & 63;
    const int sub  = tid & 3;

    const int spb = T_DIM / L_STRIP;            // strips per batch = 256
    const int b   = blk / spb;
    const int t0  = (blk - b * spb) * L_STRIP;  // multiple of 16 -> t0 % 8 == 0

    const int col = tid << 2;                   // this thread's 4 columns
    const float* __restrict__ xb = x   + ((size_t)b * T_DIM) * D_DIM + col;
    float*       __restrict__ ob = out + ((size_t)b * T_DIM + t0) * D_DIM + col;

    __shared__ float red[2][4][2];              // [parity][wave][gate, scalar]

    // ---- warm-up: rows t0-4 .. t0+PF-1 into ring (slot = row & 7) ----
    float4 s[8];
    #pragma unroll
    for (int j = 0; j < WARM + PF; ++j) {
        const int trow = (t0 - WARM + j) & (T_DIM - 1);   // circular == jnp.roll
        s[(j + 4) & 7] = *(const float4*)(xb + (size_t)trow * D_DIM);
    }
    const float4 gv = *(const float4*)(gate_w + col);

    const float ss = sigmoidf(scalar_w[0]);
    const float sb = sigmoidf(bivec_w[0]);
    const float gb = gate_b[0];

    // C0 diagonal signs for this thread's 4 blades (full table:
    // {1,1,1,-1, 1,-1,-1,-1, -1,1,1,1, 1,1,1,-1})
    float4 ws;
    if      (sub == 0) ws = make_float4( 1.f,  1.f,  1.f, -1.f);
    else if (sub == 1) ws = make_float4( 1.f, -1.f, -1.f, -1.f);
    else if (sub == 2) ws = make_float4(-1.f,  1.f,  1.f,  1.f);
    else               ws = make_float4( 1.f,  1.f,  1.f, -1.f);
    const float m3  = (sub == 0) ? 1.f : 0.f;   // elem3 <- k=3
    const float a1  = (sub == 1) ? 1.f : 0.f;   // elem1<-k=5, elem2<-k=6
    const float a2  = (sub == 2) ? 1.f : 0.f;   // elem1<-k=9, elem2<-k=10
    const float m12 = (sub == 3) ? 1.f : 0.f;   // elem0 <- k=12

    #pragma unroll
    for (int k = 0; k < L_STRIP; ++k) {
        // prefetch row t0+k+PF into the slot whose row (t0+k+PF-8) is dead
        if (k + PF < L_STRIP) {
            s[(k + PF) & 7] = *(const float4*)(xb + (size_t)(t0 + k + PF) * D_DIM);
        }

        const float4 cur = s[k & 7];            // x[t]
        const float4 p1  = s[(k + 7) & 7];      // x[t-1]
        const float4 p2  = s[(k + 6) & 7];      // x[t-2]
        const float4 p4  = s[(k + 4) & 7];      // x[t-4]

        float4 cs;  // csum = 3x - x[t-1] - x[t-2] - x[t-4]
        cs.x = 3.f * cur.x - p1.x - p2.x - p4.x;
        cs.y = 3.f * cur.y - p1.y - p2.y - p4.y;
        cs.z = 3.f * cur.z - p1.z - p2.z - p4.z;
        cs.w = 3.f * cur.w - p1.w - p2.w - p4.w;

        float gp = cur.x * gv.x + cur.y * gv.y + cur.z * gv.z + cur.w * gv.w;
        float sc = ws.x * (cur.x * cs.x) + ws.y * (cur.y * cs.y)
                 + ws.z * (cur.z * cs.z) + ws.w * (cur.w * cs.w);

        // wedge: cross-blade values via quad broadcast (quad = 4 threads = 1 chunk)
        const float x1  = swz<QB0>(cur.y), x2  = swz<QB0>(cur.z);
        const float x4b = swz<QB1>(cur.x), x8b = swz<QB2>(cur.x);
        const float c1  = swz<QB0>(cs.y),  c2  = swz<QB0>(cs.z);
        const float c4b = swz<QB1>(cs.x),  c8b = swz<QB2>(cs.x);

        const float w3  = x1 * c2  - x2  * c1;    // k=3  (e12)
        const float w5  = x1 * c4b - x4b * c1;    // k=5  (e13)
        const float w6  = x2 * c4b - x4b * c2;    // k=6  (e23)
        const float w9  = x1 * c8b - x8b * c1;    // k=9  (e14)
        const float w10 = x2 * c8b - x8b * c2;    // k=10 (e24)
        const float w12 = x4b * c8b - x8b * c4b;  // k=12 (e34)

        const float4 dl = make_float4(m12 * w12,
                                      a1 * w5 + a2 * w9,
                                      a1 * w6 + a2 * w10,
                                      m3 * w3);

        // intra-wave butterfly: wave partial over its 256 columns
        #pragma unroll
        for (int o = 32; o > 0; o >>= 1) {
            gp += __shfl_xor(gp, o, 64);
            sc += __shfl_xor(sc, o, 64);
        }

        // cross-wave exchange (double-buffered -> one barrier per row)
        const int par = k & 1;
        if (lane == 0) { red[par][wid][0] = gp; red[par][wid][1] = sc; }
        __syncthreads();
        float gsum = 0.f, scsum = 0.f;
        #pragma unroll
        for (int i = 0; i < 4; ++i) {
            gsum  += red[par][i][0];
            scsum += red[par][i][1];
        }

        const float gate = sigmoidf(gsum + gb);
        const float gsb  = gate * sb;

        float4 o4;
        o4.x = cur.x + gsb * dl.x;
        o4.y = cur.y + gsb * dl.y;
        o4.z = cur.z + gsb * dl.z;
        o4.w = cur.w + gsb * dl.w;
        if (tid == 0) o4.x += gate * ss * scsum;   // scalar part at d==0
        *(float4*)(ob + (size_t)k * D_DIM) = o4;
    }
}

extern "C" void kernel_launch(void* const* d_in, const int* in_sizes, int n_in,
                              void* d_out, int out_size, void* d_ws, size_t ws_size,
                              hipStream_t stream) {
    const float* x  = (const float*)d_in[0];
    const float* gw = (const float*)d_in[1];
    const float* gb = (const float*)d_in[2];
    const float* sw = (const float*)d_in[3];
    const float* bw = (const float*)d_in[4];
    float* out = (float*)d_out;

    const int BT      = in_sizes[0] / D_DIM;     // 8*4096 = 32768 rows
    const int nstrips = BT / L_STRIP;            // 2048 blocks
    hipLaunchKernelGGL(clifford_kernel, dim3(nstrips), dim3(256), 0, stream,
                       x, gw, gb, sw, bw, out, nstrips);
}

// Round 2
// 246.253 us; speedup vs baseline: 1.0354x; 1.0354x over previous
//
#include <hip/hip_runtime.h>
#include <math.h>

// R5: wave-private sliding-window strip. No barriers, no LDS.
//
// R3 (one wave per row): 81.9 us, latency-bound — 20 loads in flight but 5x
// read amplification; every row pays a fresh cold-start vmcnt wall.
// R4 (block strip): 90.7 us REGRESSION — prefetch depth 3 collapsed MLP and
// the per-row __syncthreads lockstepped 4 waves onto one serial
// butterfly+LDS+barrier chain.
//
// R5 keeps R4's 1.25x read amplification but removes the block coupling:
// a single wave already spans the 1024-col row (lane owns 4 float4s at
// lane*4 + m*256), so each wave privately owns a strip of L_STRIP=16 rows
// with an 8-row register ring s[8][4] (128 VGPR, static indices after full
// unroll). Per row: 4 prefetch loads (distance 3 -> 12 loads in flight),
// compute, intra-wave __shfl_xor butterfly (proven in R3), 4 stores.
// 512 blocks x 4 independent waves = 2 blocks/CU, 8 waves/CU, zero tail.
// XCD swizzle: 64 blocks = 256 strips = exactly one batch b per XCD.

constexpr int T_DIM   = 4096;
constexpr int D_DIM   = 1024;
constexpr int L_STRIP = 16;   // rows per wave
constexpr int PF      = 3;    // prefetch distance (rows)
constexpr int WARM    = 4;    // history depth (t-1, t-2, t-4)

// ds_swizzle quad-perm broadcast patterns: offset[15]=1, offset[7:0]=2-bit sels
constexpr int QB0 = 0x8000;  // all quad lanes <- quad lane 0
constexpr int QB1 = 0x8055;  // all quad lanes <- quad lane 1
constexpr int QB2 = 0x80AA;  // all quad lanes <- quad lane 2

template <int PAT>
__device__ __forceinline__ float swz(float v) {
    return __int_as_float(__builtin_amdgcn_ds_swizzle(__float_as_int(v), PAT));
}

__device__ __forceinline__ float sigmoidf(float z) {
    return 1.0f / (1.0f + __expf(-z));
}

__global__ __launch_bounds__(256, 2) void clifford_kernel(
    const float* __restrict__ x,
    const float* __restrict__ gate_w,
    const float* __restrict__ gate_b,
    const float* __restrict__ scalar_w,
    const float* __restrict__ bivec_w,
    float* __restrict__ out,
    int nstrips)
{
    // XCD-aware swizzle: contiguous strip span per XCD (one b per XCD).
    int blk = blockIdx.x;
    if ((gridDim.x & 7) == 0) {
        const int per = gridDim.x >> 3;
        blk = (blockIdx.x & 7) * per + (blockIdx.x >> 3);
    }

    const int lane  = threadIdx.x & 63;
    const int strip = blk * 4 + (threadIdx.x >> 6);   // each wave independent
    if (strip >= nstrips) return;

    const int spb = T_DIM / L_STRIP;            // strips per batch = 256
    const int b   = strip / spb;
    const int t0  = (strip - b * spb) * L_STRIP;  // multiple of 16 -> t0%8 == 0
    const int sub = lane & 3;
    const int coff = lane << 2;                 // float offset within 1KB chunk

    const float* __restrict__ xb = x + (size_t)b * T_DIM * D_DIM;
    float*       __restrict__ ob = out + ((size_t)b * T_DIM + t0) * D_DIM;

    // ---- 8-row register ring; slot = row & 7 (t0 % 8 == 0) ----
    float4 s[8][4];
    #pragma unroll
    for (int j = 0; j < WARM + PF; ++j) {       // rows t0-4 .. t0+2
        const int trow = (t0 - WARM + j) & (T_DIM - 1);   // circular == jnp.roll
        const float* __restrict__ r = xb + (size_t)trow * D_DIM + coff;
        #pragma unroll
        for (int m = 0; m < 4; ++m)
            s[(j + 4) & 7][m] = *(const float4*)(r + (m << 8));
    }
    float4 gv[4];
    #pragma unroll
    for (int m = 0; m < 4; ++m)
        gv[m] = *(const float4*)(gate_w + coff + (m << 8));

    const float ss = sigmoidf(scalar_w[0]);
    const float sb = sigmoidf(bivec_w[0]);
    const float gb = gate_b[0];

    // C0 diagonal signs for this lane's 4 blades (full table:
    // {1,1,1,-1, 1,-1,-1,-1, -1,1,1,1, 1,1,1,-1})
    float4 ws;
    if      (sub == 0) ws = make_float4( 1.f,  1.f,  1.f, -1.f);
    else if (sub == 1) ws = make_float4( 1.f, -1.f, -1.f, -1.f);
    else if (sub == 2) ws = make_float4(-1.f,  1.f,  1.f,  1.f);
    else               ws = make_float4( 1.f,  1.f,  1.f, -1.f);
    const float m3  = (sub == 0) ? 1.f : 0.f;   // elem3 <- k=3
    const float a1  = (sub == 1) ? 1.f : 0.f;   // elem1<-k=5, elem2<-k=6
    const float a2  = (sub == 2) ? 1.f : 0.f;   // elem1<-k=9, elem2<-k=10
    const float m12 = (sub == 3) ? 1.f : 0.f;   // elem0 <- k=12

    #pragma unroll
    for (int k = 0; k < L_STRIP; ++k) {
        // prefetch row t0+k+PF into the slot whose occupant is dead
        if (k + PF < L_STRIP) {
            const float* __restrict__ r =
                xb + (size_t)(t0 + k + PF) * D_DIM + coff;
            #pragma unroll
            for (int m = 0; m < 4; ++m)
                s[(k + PF) & 7][m] = *(const float4*)(r + (m << 8));
        }

        float gp = 0.f, sc = 0.f;
        float4 dl[4];

        #pragma unroll
        for (int m = 0; m < 4; ++m) {
            const float4 cur = s[k & 7][m];         // x[t]
            const float4 p1  = s[(k + 7) & 7][m];   // x[t-1]
            const float4 p2  = s[(k + 6) & 7][m];   // x[t-2]
            const float4 p4  = s[(k + 4) & 7][m];   // x[t-4]

            float4 cs;  // csum = 3x - x[t-1] - x[t-2] - x[t-4]
            cs.x = 3.f * cur.x - p1.x - p2.x - p4.x;
            cs.y = 3.f * cur.y - p1.y - p2.y - p4.y;
            cs.z = 3.f * cur.z - p1.z - p2.z - p4.z;
            cs.w = 3.f * cur.w - p1.w - p2.w - p4.w;

            gp += cur.x * gv[m].x + cur.y * gv[m].y
                + cur.z * gv[m].z + cur.w * gv[m].w;
            sc += ws.x * (cur.x * cs.x) + ws.y * (cur.y * cs.y)
                + ws.z * (cur.z * cs.z) + ws.w * (cur.w * cs.w);

            // wedge: cross-blade values via quad broadcast (quad = 1 chunk)
            const float x1  = swz<QB0>(cur.y), x2  = swz<QB0>(cur.z);
            const float x4b = swz<QB1>(cur.x), x8b = swz<QB2>(cur.x);
            const float c1  = swz<QB0>(cs.y),  c2  = swz<QB0>(cs.z);
            const float c4b = swz<QB1>(cs.x),  c8b = swz<QB2>(cs.x);

            const float w3  = x1 * c2  - x2  * c1;    // k=3  (e12)
            const float w5  = x1 * c4b - x4b * c1;    // k=5  (e13)
            const float w6  = x2 * c4b - x4b * c2;    // k=6  (e23)
            const float w9  = x1 * c8b - x8b * c1;    // k=9  (e14)
            const float w10 = x2 * c8b - x8b * c2;    // k=10 (e24)
            const float w12 = x4b * c8b - x8b * c4b;  // k=12 (e34)

            dl[m] = make_float4(m12 * w12,
                                a1 * w5 + a2 * w9,
                                a1 * w6 + a2 * w10,
                                m3 * w3);
        }

        // intra-wave butterfly: full-row reduction, all lanes get the sum
        #pragma unroll
        for (int o = 32; o > 0; o >>= 1) {
            gp += __shfl_xor(gp, o, 64);
            sc += __shfl_xor(sc, o, 64);
        }
        const float gate = sigmoidf(gp + gb);
        const float gsb  = gate * sb;

        float* __restrict__ orow = ob + (size_t)k * D_DIM + coff;
        #pragma unroll
        for (int m = 0; m < 4; ++m) {
            const float4 cur = s[k & 7][m];
            float4 o4;
            o4.x = cur.x + gsb * dl[m].x;
            o4.y = cur.y + gsb * dl[m].y;
            o4.z = cur.z + gsb * dl[m].z;
            o4.w = cur.w + gsb * dl[m].w;
            if (m == 0 && lane == 0) o4.x += gate * ss * sc;  // d==0
            *(float4*)(orow + (m << 8)) = o4;
        }
    }
}

extern "C" void kernel_launch(void* const* d_in, const int* in_sizes, int n_in,
                              void* d_out, int out_size, void* d_ws, size_t ws_size,
                              hipStream_t stream) {
    const float* x  = (const float*)d_in[0];
    const float* gw = (const float*)d_in[1];
    const float* gb = (const float*)d_in[2];
    const float* sw = (const float*)d_in[3];
    const float* bw = (const float*)d_in[4];
    float* out = (float*)d_out;

    const int BT      = in_sizes[0] / D_DIM;     // 8*4096 = 32768 rows
    const int nstrips = BT / L_STRIP;            // 2048 wave-strips
    const int blocks  = (nstrips + 3) / 4;       // 4 independent waves/block
    hipLaunchKernelGGL(clifford_kernel, dim3(blocks), dim3(256), 0, stream,
                       x, gw, gb, sw, bw, out, nstrips);
}